// Round 1
// baseline (17.406 us; speedup 1.0000x reference)
//
#include <hip/hip_runtime.h>

// LocalPlanarGuidance: x [B=16, C=4, H=96, W=128] fp32, r=8
// out[b, hh, ww] = x[b,3,h,w] / (x[b,0,h,w]*u + x[b,1,h,w]*v + x[b,2,h,w])
// h=hh/8, w=ww/8, u=((ww%8)-3.5)/8, v=((hh%8)-3.5)/8
// Output [16, 768, 1024] fp32.

#define LPG_B 16
#define LPG_H 96
#define LPG_W 128
#define LPG_R 8
#define LPG_HOUT (LPG_H * LPG_R)   // 768
#define LPG_WOUT (LPG_W * LPG_R)   // 1024
#define PLANE (LPG_H * LPG_W)      // 12288

__global__ __launch_bounds__(256) void lpg_kernel(const float* __restrict__ x,
                                                  float* __restrict__ out) {
    // One thread per (b, hh, w): produces 8 consecutive output columns.
    // total threads = B * HOUT * W = 16*768*128 = 1,572,864
    const int t = blockIdx.x * blockDim.x + threadIdx.x;

    const int w = t & (LPG_W - 1);       // W = 128 (pow2)
    const int rest = t >> 7;             // b*HOUT + hh
    const int hh = rest % LPG_HOUT;      // 768 -> magic-mul division
    const int b = rest / LPG_HOUT;

    const int h = hh >> 3;
    const float v = ((float)(hh & 7) - 3.5f) * 0.125f;

    // Input loads: 4 planes, stride PLANE. Coalesced across lanes (w contiguous).
    const int in_base = ((b * 4) * LPG_H + h) * LPG_W + w;
    const float p0 = x[in_base];               // channel 0 (u coeff)
    const float p1 = x[in_base + PLANE];       // channel 1 (v coeff)
    const float p2 = x[in_base + 2 * PLANE];   // channel 2 (const)
    const float p3 = x[in_base + 3 * PLANE];   // channel 3 (numerator)

    const float base = p1 * v + p2;

    float o[8];
#pragma unroll
    for (int j = 0; j < 8; ++j) {
        const float u = ((float)j - 3.5f) * 0.125f;
        o[j] = p3 / (p0 * u + base);
    }

    float* dst = out + ((size_t)(b * LPG_HOUT + hh) * LPG_WOUT + (w << 3));
    *reinterpret_cast<float4*>(dst)     = make_float4(o[0], o[1], o[2], o[3]);
    *reinterpret_cast<float4*>(dst + 4) = make_float4(o[4], o[5], o[6], o[7]);
}

extern "C" void kernel_launch(void* const* d_in, const int* in_sizes, int n_in,
                              void* d_out, int out_size, void* d_ws, size_t ws_size,
                              hipStream_t stream) {
    (void)in_sizes; (void)n_in; (void)d_ws; (void)ws_size; (void)out_size;
    const float* x = (const float*)d_in[0];
    float* out = (float*)d_out;

    const int total_threads = LPG_B * LPG_HOUT * LPG_W;  // 1,572,864
    const int block = 256;
    const int grid = total_threads / block;              // 6144
    lpg_kernel<<<grid, block, 0, stream>>>(x, out);
}

// Round 2
// 16.968 us; speedup vs baseline: 1.0258x; 1.0258x over previous
//
#include <hip/hip_runtime.h>

// LocalPlanarGuidance: x [B=16, C=4, H=96, W=128] fp32, r=8
// out[b, hh, ww] = x[b,3,h,w] / (x[b,0,h,w]*u + x[b,1,h,w]*v + x[b,2,h,w])
// h=hh/8, w=ww/8, u=((ww%8)-3.5)/8, v=((hh%8)-3.5)/8
// Output [16, 768, 1024] fp32.
//
// Mapping: one thread -> one float4 of output (4 consecutive ww).
// Lane i stores 16B contiguous -> perfectly coalesced 1KB/wave stores.
// Inputs (3MB) are L2/L3-resident; the 2x duplicate load is free.
// Divide replaced with v_rcp_f32 (rel err ~2^-22, threshold is 1.7e-2).

#define LPG_B 16
#define LPG_H 96
#define LPG_W 128
#define LPG_HOUT 768
#define LPG_WOUT 1024
#define PLANE (LPG_H * LPG_W)      // 12288

__global__ __launch_bounds__(256) void lpg_kernel(const float* __restrict__ x,
                                                  float* __restrict__ out) {
    // total threads = B * HOUT * (WOUT/4) = 16*768*256 = 3,145,728
    const int t = blockIdx.x * blockDim.x + threadIdx.x;

    const int wq = t & 255;              // quad index within row (WOUT/4 = 256)
    const int rest = t >> 8;             // b*HOUT + hh
    const int hh = rest % LPG_HOUT;      // magic-mul division
    const int b = rest / LPG_HOUT;

    const int w = wq >> 1;               // input column (two quads per input col)
    const int jbase = (wq & 1) << 2;     // 0 or 4: which half of the 8-wide cell
    const int h = hh >> 3;
    const float v = ((float)(hh & 7) - 3.5f) * 0.125f;

    const int in_base = ((b * 4) * LPG_H + h) * LPG_W + w;
    const float p0 = x[in_base];               // channel 0 (u coeff)
    const float p1 = x[in_base + PLANE];       // channel 1 (v coeff)
    const float p2 = x[in_base + 2 * PLANE];   // channel 2 (const)
    const float p3 = x[in_base + 3 * PLANE];   // channel 3 (numerator)

    const float base = fmaf(p1, v, p2);

    float o[4];
#pragma unroll
    for (int j = 0; j < 4; ++j) {
        const float u = ((float)(jbase + j) - 3.5f) * 0.125f;
        const float denom = fmaf(p0, u, base);
        o[j] = p3 * __builtin_amdgcn_rcpf(denom);
    }

    float4* dst = reinterpret_cast<float4*>(
        out + ((size_t)(b * LPG_HOUT + hh) * LPG_WOUT) + (wq << 2));
    *dst = make_float4(o[0], o[1], o[2], o[3]);
}

extern "C" void kernel_launch(void* const* d_in, const int* in_sizes, int n_in,
                              void* d_out, int out_size, void* d_ws, size_t ws_size,
                              hipStream_t stream) {
    (void)in_sizes; (void)n_in; (void)d_ws; (void)ws_size; (void)out_size;
    const float* x = (const float*)d_in[0];
    float* out = (float*)d_out;

    const int total_threads = LPG_B * LPG_HOUT * (LPG_WOUT / 4);  // 3,145,728
    const int block = 256;
    const int grid = total_threads / block;                       // 12288
    lpg_kernel<<<grid, block, 0, stream>>>(x, out);
}